// Round 4
// baseline (447.276 us; speedup 1.0000x reference)
//
#include <hip/hip_runtime.h>
#include <stdint.h>
#include <math.h>

// ---------------------------------------------------------------------------
// Sampler: temperature-scale -> top-k threshold -> Gumbel-max categorical.
// Exact reproduction of the JAX reference (threefry partitionable, key 42).
//
// R3 structure: two kernels.
//   collect  : B*SEG blocks x 256 thr, no LDS. Stream segments, append all
//              x >= SPEC_F (candidate superset) to per-row lists in d_ws.
//   finalize : B blocks x 1024 thr. Candidates -> LDS, exact kth refinement,
//              exact division filter, gumbel-argmax. Per-row fallback to the
//              full-histogram algorithm (L3-warm re-read) if speculation
//              failed. Monolithic R2 kernel retained for tiny ws_size.
// ---------------------------------------------------------------------------

#define BLOCK 1024
#define CBLOCK 256
#define SEG 16
#define NBIN  4096
#define CAP   4096
#define SLACK 64u
#define SPEC_F 2.5f
#define SPEC_KEY 0xC0200000u   // f2key(2.5f)

__device__ __forceinline__ uint32_t rotl32(uint32_t x, uint32_t r) {
  return (x << r) | (x >> (32u - r));
}

__device__ __forceinline__ uint32_t f2key(float x) {
  uint32_t b = __float_as_uint(x);
  return (b & 0x80000000u) ? ~b : (b | 0x80000000u);
}
__device__ __forceinline__ float key2f(uint32_t k) {
  uint32_t b = (k & 0x80000000u) ? (k & 0x7FFFFFFFu) : ~k;
  return __uint_as_float(b);
}

// Threefry-2x32, key = (0, 42)
__device__ __forceinline__ void tf2x32(uint32_t x0, uint32_t x1,
                                       uint32_t &o0, uint32_t &o1) {
  const uint32_t k0 = 0u, k1 = 42u;
  const uint32_t k2 = k0 ^ k1 ^ 0x1BD11BDAu;
  x0 += k0; x1 += k1;
#define TF_R(r) { x0 += x1; x1 = rotl32(x1, (r)); x1 ^= x0; }
  TF_R(13u) TF_R(15u) TF_R(26u) TF_R(6u)
  x0 += k1; x1 += k2 + 1u;
  TF_R(17u) TF_R(29u) TF_R(16u) TF_R(24u)
  x0 += k2; x1 += k0 + 2u;
  TF_R(13u) TF_R(15u) TF_R(26u) TF_R(6u)
  x0 += k0; x1 += k1 + 3u;
  TF_R(17u) TF_R(29u) TF_R(16u) TF_R(24u)
  x0 += k1; x1 += k2 + 4u;
  TF_R(13u) TF_R(15u) TF_R(26u) TF_R(6u)
  x0 += k2; x1 += k0 + 5u;
#undef TF_R
  o0 = x0; o1 = x1;
}

__device__ __forceinline__ float gumbel_at(uint32_t j) {
  uint32_t o0, o1;
  tf2x32(0u, j, o0, o1);
  uint32_t bits = o0 ^ o1;
  float f = __uint_as_float((bits >> 9) | 0x3F800000u) - 1.0f;
  const float TINY = 1.17549435e-38f;
  float u = (f == 0.0f) ? TINY : f;
  return -logf(-logf(u));
}

// descending-rank select over hist[4096]; bin + 1-based in-bin rank
__device__ void find4096(uint32_t* hist, uint32_t* super, uint32_t Kt,
                         uint32_t* s_bin, uint32_t* s_rank) {
  const int tid = threadIdx.x;
  if (tid < 64) {
    uint32_t s = 0;
    for (int i = 0; i < 64; ++i) s += hist[tid * 64 + i];
    super[tid] = s;
  }
  __syncthreads();
  if (tid == 0) {
    uint32_t acc = 0; int sb = 0;
    for (int s = 63; s >= 0; --s) {
      if (acc + super[s] >= Kt) { sb = s; break; }
      acc += super[s];
    }
    uint32_t bfound = (uint32_t)(sb * 64);
    for (int i = 63; i >= 0; --i) {
      uint32_t bin = (uint32_t)(sb * 64 + i);
      if (acc + hist[bin] >= Kt) { bfound = bin; break; }
      acc += hist[bin];
    }
    *s_bin = bfound; *s_rank = Kt - acc;
  }
  __syncthreads();
}

// exact kth-largest among cand[0:cnt], 3-level LDS refinement
__device__ void kth_of_cand(const uint32_t* cand_key, uint32_t cnt, uint32_t K,
                            uint32_t* hist, uint32_t* super,
                            uint32_t* s_bin, uint32_t* s_rank, uint32_t* s_kth) {
  const int tid = threadIdx.x;
  for (int i = tid; i < NBIN; i += BLOCK) hist[i] = 0u;
  __syncthreads();
  for (int i = tid; i < (int)cnt; i += BLOCK)
    atomicAdd(&hist[cand_key[i] >> 20], 1u);
  __syncthreads();
  find4096(hist, super, K, s_bin, s_rank);
  const uint32_t bA = *s_bin; const uint32_t rA = *s_rank;

  for (int i = tid; i < NBIN; i += BLOCK) hist[i] = 0u;
  __syncthreads();
  for (int i = tid; i < (int)cnt; i += BLOCK) {
    uint32_t key = cand_key[i];
    if ((key >> 20) == bA) atomicAdd(&hist[(key >> 8) & 0xFFFu], 1u);
  }
  __syncthreads();
  find4096(hist, super, rA, s_bin, s_rank);
  const uint32_t bB = *s_bin; const uint32_t rB = *s_rank;

  for (int i = tid; i < 256; i += BLOCK) hist[i] = 0u;
  __syncthreads();
  for (int i = tid; i < (int)cnt; i += BLOCK) {
    uint32_t key = cand_key[i];
    if ((key >> 8) == ((bA << 12) | bB)) atomicAdd(&hist[key & 0xFFu], 1u);
  }
  __syncthreads();
  if (tid == 0) {
    uint32_t acc = 0; uint32_t b3 = 0;
    for (int i = 255; i >= 0; --i) {
      if (acc + hist[i] >= rB) { b3 = (uint32_t)i; break; }
      acc += hist[i];
    }
    *s_kth = (bA << 20) | (bB << 8) | b3;
  }
  __syncthreads();
}

__device__ void gumbel_argmax_cand(const uint32_t* cand_key, const int* cand_idx,
                                   uint32_t cnt, float kth_scaled, float temp,
                                   uint32_t jbase, uint32_t* hist,
                                   int* out, int r) {
  const int tid = threadIdx.x;
  float bv = -INFINITY;
  int bi = 0x7FFFFFFF;
  for (int i = tid; i < (int)cnt; i += BLOCK) {
    float sc = key2f(cand_key[i]) / temp;
    if (sc >= kth_scaled) {
      int v = cand_idx[i];
      float g = gumbel_at(jbase + (uint32_t)v);
      float val = sc + g;
      if (val > bv || (val == bv && v < bi)) { bv = val; bi = v; }
    }
  }
  __syncthreads();
  float* rv = (float*)hist;
  int*   ri = (int*)(hist + BLOCK);
  rv[tid] = bv; ri[tid] = bi;
  __syncthreads();
  for (int s = BLOCK >> 1; s > 0; s >>= 1) {
    if (tid < s) {
      float ov = rv[tid + s]; int oi = ri[tid + s];
      if (ov > rv[tid] || (ov == rv[tid] && oi < ri[tid])) {
        rv[tid] = ov; ri[tid] = oi;
      }
    }
    __syncthreads();
  }
  if (tid == 0) out[r] = ri[0];
}

// ======================= R3 kernel 1: collect ==============================
__global__ __launch_bounds__(CBLOCK)
void collect_kernel(const float* __restrict__ logits, int V,
                    uint32_t* __restrict__ cnts, uint2* __restrict__ entries,
                    uint32_t cap) {
  const int r   = blockIdx.x / SEG;
  const int seg = blockIdx.x % SEG;
  const int tid = threadIdx.x;
  const float* row = logits + (size_t)r * (size_t)V;
  const float4* row4 = (const float4*)row;
  const int n4 = V >> 2;
  const int chunk = (n4 + SEG - 1) / SEG;
  const int s4 = seg * chunk;
  const int e4 = min(n4, s4 + chunk);
  uint32_t* cnt = cnts + r;
  uint2* ent = entries + (size_t)r * cap;

  int i = s4 + tid;
  // 4-deep independent loads per iteration
  for (; i + 3 * CBLOCK < e4; i += 4 * CBLOCK) {
    float4 a = row4[i];
    float4 b = row4[i + CBLOCK];
    float4 c = row4[i + 2 * CBLOCK];
    float4 d = row4[i + 3 * CBLOCK];
#define PROC(vec, base)                                                        \
    {                                                                          \
      if (vec.x >= SPEC_F) { uint32_t p = atomicAdd(cnt, 1u);                  \
        if (p < cap) ent[p] = make_uint2(f2key(vec.x), (uint32_t)(((base) << 2) + 0)); } \
      if (vec.y >= SPEC_F) { uint32_t p = atomicAdd(cnt, 1u);                  \
        if (p < cap) ent[p] = make_uint2(f2key(vec.y), (uint32_t)(((base) << 2) + 1)); } \
      if (vec.z >= SPEC_F) { uint32_t p = atomicAdd(cnt, 1u);                  \
        if (p < cap) ent[p] = make_uint2(f2key(vec.z), (uint32_t)(((base) << 2) + 2)); } \
      if (vec.w >= SPEC_F) { uint32_t p = atomicAdd(cnt, 1u);                  \
        if (p < cap) ent[p] = make_uint2(f2key(vec.w), (uint32_t)(((base) << 2) + 3)); } \
    }
    PROC(a, i)
    PROC(b, i + CBLOCK)
    PROC(c, i + 2 * CBLOCK)
    PROC(d, i + 3 * CBLOCK)
  }
  for (; i < e4; i += CBLOCK) {
    float4 a = row4[i];
    PROC(a, i)
  }
#undef PROC
  // scalar tail of the row (V % 4), handled by the last segment
  if (seg == SEG - 1) {
    for (int j = (n4 << 2) + tid; j < V; j += CBLOCK) {
      float x = row[j];
      if (x >= SPEC_F) {
        uint32_t p = atomicAdd(cnt, 1u);
        if (p < cap) ent[p] = make_uint2(f2key(x), (uint32_t)j);
      }
    }
  }
}

// ======================= R3 kernel 2: finalize =============================
__global__ __launch_bounds__(BLOCK)
void finalize_kernel(const float* __restrict__ logits,
                     const float* __restrict__ temps,
                     const int* __restrict__ topk_p,
                     int* __restrict__ out, int V,
                     const uint32_t* __restrict__ cnts,
                     const uint2* __restrict__ entries, uint32_t cap) {
  const int r = blockIdx.x;
  const int tid = threadIdx.x;
  const uint32_t K = (uint32_t)(*topk_p);
  const float temp = temps[r];
  const float* row = logits + (size_t)r * (size_t)V;
  const uint32_t jbase = (uint32_t)r * (uint32_t)V;

  __shared__ uint32_t hist[NBIN];
  __shared__ uint32_t super[64];
  __shared__ uint32_t cand_key[CAP];
  __shared__ int      cand_idx[CAP];
  __shared__ uint32_t s_cnt, s_bin, s_rank, s_kth;
  __shared__ float    s_kth_scaled;

  const uint32_t cnt = cnts[r];

  if (cnt >= K && cnt <= cap) {
    const uint2* ent = entries + (size_t)r * cap;
    for (int i = tid; i < (int)cnt; i += BLOCK) {
      uint2 e = ent[i];
      cand_key[i] = e.x; cand_idx[i] = (int)e.y;
    }
    __syncthreads();
    kth_of_cand(cand_key, cnt, K, hist, super, &s_bin, &s_rank, &s_kth);
    const uint32_t kth_key = s_kth;
    if (kth_key >= SPEC_KEY + SLACK) {
      if (tid == 0) s_kth_scaled = key2f(kth_key) / temp;
      __syncthreads();
      gumbel_argmax_cand(cand_key, cand_idx, cnt, s_kth_scaled, temp,
                         jbase, hist, out, r);
      return;
    }
    __syncthreads();
  }

  // ---------------- fallback: full histogram algorithm (L3-warm) ----------
  const int n4 = V >> 2;
  const float4* row4 = (const float4*)row;
  for (int i = tid; i < NBIN; i += BLOCK) hist[i] = 0u;
  if (tid == 0) s_cnt = 0u;
  __syncthreads();
  for (int i = tid; i < n4; i += BLOCK) {
    float4 x = row4[i];
    atomicAdd(&hist[f2key(x.x) >> 20], 1u);
    atomicAdd(&hist[f2key(x.y) >> 20], 1u);
    atomicAdd(&hist[f2key(x.z) >> 20], 1u);
    atomicAdd(&hist[f2key(x.w) >> 20], 1u);
  }
  for (int i = (n4 << 2) + tid; i < V; i += BLOCK)
    atomicAdd(&hist[f2key(row[i]) >> 20], 1u);
  __syncthreads();
  find4096(hist, super, K, &s_bin, &s_rank);
  const uint32_t b1 = s_bin;
  const uint32_t r1 = s_rank;

  uint32_t lo = b1 << 20;
  lo = (lo >= SLACK) ? (lo - SLACK) : 0u;
  for (int i = tid; i < n4; i += BLOCK) {
    float4 x = row4[i];
    float s[4] = {x.x, x.y, x.z, x.w};
#pragma unroll
    for (int q = 0; q < 4; ++q) {
      uint32_t key = f2key(s[q]);
      if (key >= lo) {
        uint32_t p = atomicAdd(&s_cnt, 1u);
        if (p < CAP) { cand_key[p] = key; cand_idx[p] = (i << 2) + q; }
      }
    }
  }
  for (int i = (n4 << 2) + tid; i < V; i += BLOCK) {
    uint32_t key = f2key(row[i]);
    if (key >= lo) {
      uint32_t p = atomicAdd(&s_cnt, 1u);
      if (p < CAP) { cand_key[p] = key; cand_idx[p] = i; }
    }
  }
  __syncthreads();
  const uint32_t cnt2 = s_cnt;

  if (cnt2 <= CAP) {
    kth_of_cand(cand_key, cnt2, K, hist, super, &s_bin, &s_rank, &s_kth);
    if (tid == 0) s_kth_scaled = key2f(s_kth) / temp;
    __syncthreads();
    gumbel_argmax_cand(cand_key, cand_idx, cnt2, s_kth_scaled, temp,
                       jbase, hist, out, r);
    return;
  }

  // pathological duplicate-heavy rows: refine from global memory
  for (int i = tid; i < NBIN; i += BLOCK) hist[i] = 0u;
  __syncthreads();
  for (int i = tid; i < V; i += BLOCK) {
    uint32_t key = f2key(row[i]);
    if ((key >> 20) == b1) atomicAdd(&hist[(key >> 8) & 0xFFFu], 1u);
  }
  __syncthreads();
  find4096(hist, super, r1, &s_bin, &s_rank);
  const uint32_t b2 = s_bin; const uint32_t r2 = s_rank;
  for (int i = tid; i < 256; i += BLOCK) hist[i] = 0u;
  __syncthreads();
  for (int i = tid; i < V; i += BLOCK) {
    uint32_t key = f2key(row[i]);
    if ((key >> 8) == ((b1 << 12) | b2)) atomicAdd(&hist[key & 0xFFu], 1u);
  }
  __syncthreads();
  if (tid == 0) {
    uint32_t acc = 0; uint32_t b3 = 0;
    for (int i = 255; i >= 0; --i) {
      if (acc + hist[i] >= r2) { b3 = (uint32_t)i; break; }
      acc += hist[i];
    }
    uint32_t kth = (b1 << 20) | (b2 << 8) | b3;
    s_kth = kth;
    s_kth_scaled = key2f(kth) / temp;
  }
  __syncthreads();
  const uint32_t kth_key = s_kth;
  const float kth_scaled = s_kth_scaled;
  uint32_t lo2 = (kth_key >= SLACK) ? (kth_key - SLACK) : 0u;

  float bv = -INFINITY;
  int bi = 0x7FFFFFFF;
  for (int i = tid; i < V; i += BLOCK) {
    float x = row[i];
    uint32_t key = f2key(x);
    if (key >= lo2) {
      float sc = x / temp;
      if (sc >= kth_scaled) {
        float g = gumbel_at(jbase + (uint32_t)i);
        float val = sc + g;
        if (val > bv || (val == bv && i < bi)) { bv = val; bi = i; }
      }
    }
  }
  __syncthreads();
  float* rv = (float*)hist;
  int*   ri = (int*)(hist + BLOCK);
  rv[tid] = bv; ri[tid] = bi;
  __syncthreads();
  for (int s = BLOCK >> 1; s > 0; s >>= 1) {
    if (tid < s) {
      float ov = rv[tid + s]; int oi = ri[tid + s];
      if (ov > rv[tid] || (ov == rv[tid] && oi < ri[tid])) {
        rv[tid] = ov; ri[tid] = oi;
      }
    }
    __syncthreads();
  }
  if (tid == 0) out[r] = ri[0];
}

// ============== monolithic R2 kernel (used only if ws too small) ===========
__global__ __launch_bounds__(BLOCK)
void sampler_mono(const float* __restrict__ logits,
                  const float* __restrict__ temps,
                  const int* __restrict__ topk_p,
                  int* __restrict__ out, int B, int V) {
  const int r = blockIdx.x;
  const int tid = threadIdx.x;
  const uint32_t K = (uint32_t)(*topk_p);
  const float temp = temps[r];
  const float* row = logits + (size_t)r * (size_t)V;
  const uint32_t jbase = (uint32_t)r * (uint32_t)V;

  __shared__ uint32_t hist[NBIN];
  __shared__ uint32_t super[64];
  __shared__ uint32_t cand_key[CAP];
  __shared__ int      cand_idx[CAP];
  __shared__ uint32_t s_cnt, s_bin, s_rank, s_kth;
  __shared__ float    s_kth_scaled;

  const int n4 = V >> 2;
  const float4* row4 = (const float4*)row;

  if (tid == 0) s_cnt = 0u;
  __syncthreads();
  for (int i = tid; i < n4; i += BLOCK) {
    float4 x = row4[i];
    float s[4] = {x.x, x.y, x.z, x.w};
#pragma unroll
    for (int q = 0; q < 4; ++q) {
      if (s[q] >= SPEC_F) {
        uint32_t p = atomicAdd(&s_cnt, 1u);
        if (p < CAP) { cand_key[p] = f2key(s[q]); cand_idx[p] = (i << 2) + q; }
      }
    }
  }
  for (int i = (n4 << 2) + tid; i < V; i += BLOCK) {
    float x = row[i];
    if (x >= SPEC_F) {
      uint32_t p = atomicAdd(&s_cnt, 1u);
      if (p < CAP) { cand_key[p] = f2key(x); cand_idx[p] = i; }
    }
  }
  __syncthreads();
  const uint32_t cnt = s_cnt;

  if (cnt >= K && cnt <= CAP) {
    kth_of_cand(cand_key, cnt, K, hist, super, &s_bin, &s_rank, &s_kth);
    const uint32_t kth_key = s_kth;
    if (kth_key >= SPEC_KEY + SLACK) {
      if (tid == 0) s_kth_scaled = key2f(kth_key) / temp;
      __syncthreads();
      gumbel_argmax_cand(cand_key, cand_idx, cnt, s_kth_scaled, temp,
                         jbase, hist, out, r);
      return;
    }
    __syncthreads();
  }

  for (int i = tid; i < NBIN; i += BLOCK) hist[i] = 0u;
  if (tid == 0) s_cnt = 0u;
  __syncthreads();
  for (int i = tid; i < n4; i += BLOCK) {
    float4 x = row4[i];
    atomicAdd(&hist[f2key(x.x) >> 20], 1u);
    atomicAdd(&hist[f2key(x.y) >> 20], 1u);
    atomicAdd(&hist[f2key(x.z) >> 20], 1u);
    atomicAdd(&hist[f2key(x.w) >> 20], 1u);
  }
  for (int i = (n4 << 2) + tid; i < V; i += BLOCK)
    atomicAdd(&hist[f2key(row[i]) >> 20], 1u);
  __syncthreads();
  find4096(hist, super, K, &s_bin, &s_rank);
  const uint32_t b1 = s_bin;
  const uint32_t r1 = s_rank;

  uint32_t lo = b1 << 20;
  lo = (lo >= SLACK) ? (lo - SLACK) : 0u;
  for (int i = tid; i < n4; i += BLOCK) {
    float4 x = row4[i];
    float s[4] = {x.x, x.y, x.z, x.w};
#pragma unroll
    for (int q = 0; q < 4; ++q) {
      uint32_t key = f2key(s[q]);
      if (key >= lo) {
        uint32_t p = atomicAdd(&s_cnt, 1u);
        if (p < CAP) { cand_key[p] = key; cand_idx[p] = (i << 2) + q; }
      }
    }
  }
  for (int i = (n4 << 2) + tid; i < V; i += BLOCK) {
    uint32_t key = f2key(row[i]);
    if (key >= lo) {
      uint32_t p = atomicAdd(&s_cnt, 1u);
      if (p < CAP) { cand_key[p] = key; cand_idx[p] = i; }
    }
  }
  __syncthreads();
  const uint32_t cnt2 = s_cnt;

  if (cnt2 <= CAP) {
    kth_of_cand(cand_key, cnt2, K, hist, super, &s_bin, &s_rank, &s_kth);
    if (tid == 0) s_kth_scaled = key2f(s_kth) / temp;
    __syncthreads();
    gumbel_argmax_cand(cand_key, cand_idx, cnt2, s_kth_scaled, temp,
                       jbase, hist, out, r);
    return;
  }

  for (int i = tid; i < NBIN; i += BLOCK) hist[i] = 0u;
  __syncthreads();
  for (int i = tid; i < V; i += BLOCK) {
    uint32_t key = f2key(row[i]);
    if ((key >> 20) == b1) atomicAdd(&hist[(key >> 8) & 0xFFFu], 1u);
  }
  __syncthreads();
  find4096(hist, super, r1, &s_bin, &s_rank);
  const uint32_t b2 = s_bin; const uint32_t r2 = s_rank;
  for (int i = tid; i < 256; i += BLOCK) hist[i] = 0u;
  __syncthreads();
  for (int i = tid; i < V; i += BLOCK) {
    uint32_t key = f2key(row[i]);
    if ((key >> 8) == ((b1 << 12) | b2)) atomicAdd(&hist[key & 0xFFu], 1u);
  }
  __syncthreads();
  if (tid == 0) {
    uint32_t acc = 0; uint32_t b3 = 0;
    for (int i = 255; i >= 0; --i) {
      if (acc + hist[i] >= r2) { b3 = (uint32_t)i; break; }
      acc += hist[i];
    }
    uint32_t kth = (b1 << 20) | (b2 << 8) | b3;
    s_kth = kth;
    s_kth_scaled = key2f(kth) / temp;
  }
  __syncthreads();
  const uint32_t kth_key = s_kth;
  const float kth_scaled = s_kth_scaled;
  uint32_t lo2 = (kth_key >= SLACK) ? (kth_key - SLACK) : 0u;

  float bv = -INFINITY;
  int bi = 0x7FFFFFFF;
  for (int i = tid; i < V; i += BLOCK) {
    float x = row[i];
    uint32_t key = f2key(x);
    if (key >= lo2) {
      float sc = x / temp;
      if (sc >= kth_scaled) {
        float g = gumbel_at(jbase + (uint32_t)i);
        float val = sc + g;
        if (val > bv || (val == bv && i < bi)) { bv = val; bi = i; }
      }
    }
  }
  __syncthreads();
  float* rv = (float*)hist;
  int*   ri = (int*)(hist + BLOCK);
  rv[tid] = bv; ri[tid] = bi;
  __syncthreads();
  for (int s = BLOCK >> 1; s > 0; s >>= 1) {
    if (tid < s) {
      float ov = rv[tid + s]; int oi = ri[tid + s];
      if (ov > rv[tid] || (ov == rv[tid] && oi < ri[tid])) {
        rv[tid] = ov; ri[tid] = oi;
      }
    }
    __syncthreads();
  }
  if (tid == 0) out[r] = ri[0];
}

extern "C" void kernel_launch(void* const* d_in, const int* in_sizes, int n_in,
                              void* d_out, int out_size, void* d_ws, size_t ws_size,
                              hipStream_t stream) {
  const float* logits = (const float*)d_in[0];
  const float* temps  = (const float*)d_in[1];
  const int*   topk   = (const int*)d_in[2];
  int* out = (int*)d_out;
  const int B = in_sizes[1];           // 256
  const int V = in_sizes[0] / B;       // 128000

  const size_t cnt_bytes = (size_t)B * sizeof(uint32_t);
  size_t cap = 0;
  if (ws_size > cnt_bytes + 4096)
    cap = (ws_size - cnt_bytes) / ((size_t)B * sizeof(uint2));
  if (cap > CAP) cap = CAP;

  if (cap >= 512) {
    uint32_t* cnts = (uint32_t*)d_ws;
    uint2* entries = (uint2*)((char*)d_ws + cnt_bytes);
    hipMemsetAsync(d_ws, 0, cnt_bytes, stream);
    collect_kernel<<<B * SEG, CBLOCK, 0, stream>>>(logits, V, cnts, entries,
                                                   (uint32_t)cap);
    finalize_kernel<<<B, BLOCK, 0, stream>>>(logits, temps, topk, out, V,
                                             cnts, entries, (uint32_t)cap);
  } else {
    sampler_mono<<<B, BLOCK, 0, stream>>>(logits, temps, topk, out, B, V);
  }
}

// Round 5
// 59.202 us; speedup vs baseline: 7.5551x; 7.5551x over previous
//
#include <hip/hip_runtime.h>
#include <stdint.h>
#include <math.h>

// ---------------------------------------------------------------------------
// Sampler: temperature-scale -> top-k threshold -> Gumbel-max categorical.
// Exact reproduction of the JAX reference (threefry partitionable, key 42).
//
// R4 structure: two kernels, ZERO global atomics (R3's collect spent 414us
// serializing ~200k device-scope atomics into 16 cachelines).
//   collect  : B*SEG blocks x 256 thr. Stream segment, append x >= SPEC_F to
//              a small LDS buffer (LDS atomic), then copy to the block's
//              PRIVATE slot in d_ws + write per-segment count. Deterministic.
//   finalize : B blocks x 1024 thr. Prefix-sum 16 segment counts, gather
//              candidates to LDS, exact kth refinement, exact division
//              filter, gumbel-argmax. Per-row fallback to full-histogram
//              algorithm (L3-warm re-read) if speculation failed.
// ---------------------------------------------------------------------------

#define BLOCK 1024
#define CBLOCK 256
#define SEG 16
#define LCAP 512        // per-block LDS candidate buffer
#define NBIN  4096
#define CAP   4096
#define SLACK 64u
#define SPEC_F 2.5f
#define SPEC_KEY 0xC0200000u   // f2key(2.5f)

__device__ __forceinline__ uint32_t rotl32(uint32_t x, uint32_t r) {
  return (x << r) | (x >> (32u - r));
}

__device__ __forceinline__ uint32_t f2key(float x) {
  uint32_t b = __float_as_uint(x);
  return (b & 0x80000000u) ? ~b : (b | 0x80000000u);
}
__device__ __forceinline__ float key2f(uint32_t k) {
  uint32_t b = (k & 0x80000000u) ? (k & 0x7FFFFFFFu) : ~k;
  return __uint_as_float(b);
}

// Threefry-2x32, key = (0, 42)
__device__ __forceinline__ void tf2x32(uint32_t x0, uint32_t x1,
                                       uint32_t &o0, uint32_t &o1) {
  const uint32_t k0 = 0u, k1 = 42u;
  const uint32_t k2 = k0 ^ k1 ^ 0x1BD11BDAu;
  x0 += k0; x1 += k1;
#define TF_R(r) { x0 += x1; x1 = rotl32(x1, (r)); x1 ^= x0; }
  TF_R(13u) TF_R(15u) TF_R(26u) TF_R(6u)
  x0 += k1; x1 += k2 + 1u;
  TF_R(17u) TF_R(29u) TF_R(16u) TF_R(24u)
  x0 += k2; x1 += k0 + 2u;
  TF_R(13u) TF_R(15u) TF_R(26u) TF_R(6u)
  x0 += k0; x1 += k1 + 3u;
  TF_R(17u) TF_R(29u) TF_R(16u) TF_R(24u)
  x0 += k1; x1 += k2 + 4u;
  TF_R(13u) TF_R(15u) TF_R(26u) TF_R(6u)
  x0 += k2; x1 += k0 + 5u;
#undef TF_R
  o0 = x0; o1 = x1;
}

__device__ __forceinline__ float gumbel_at(uint32_t j) {
  uint32_t o0, o1;
  tf2x32(0u, j, o0, o1);
  uint32_t bits = o0 ^ o1;
  float f = __uint_as_float((bits >> 9) | 0x3F800000u) - 1.0f;
  const float TINY = 1.17549435e-38f;
  float u = (f == 0.0f) ? TINY : f;
  return -logf(-logf(u));
}

// descending-rank select over hist[4096]; bin + 1-based in-bin rank
__device__ void find4096(uint32_t* hist, uint32_t* super, uint32_t Kt,
                         uint32_t* s_bin, uint32_t* s_rank) {
  const int tid = threadIdx.x;
  if (tid < 64) {
    uint32_t s = 0;
    for (int i = 0; i < 64; ++i) s += hist[tid * 64 + i];
    super[tid] = s;
  }
  __syncthreads();
  if (tid == 0) {
    uint32_t acc = 0; int sb = 0;
    for (int s = 63; s >= 0; --s) {
      if (acc + super[s] >= Kt) { sb = s; break; }
      acc += super[s];
    }
    uint32_t bfound = (uint32_t)(sb * 64);
    for (int i = 63; i >= 0; --i) {
      uint32_t bin = (uint32_t)(sb * 64 + i);
      if (acc + hist[bin] >= Kt) { bfound = bin; break; }
      acc += hist[bin];
    }
    *s_bin = bfound; *s_rank = Kt - acc;
  }
  __syncthreads();
}

// exact kth-largest among cand[0:cnt], 3-level LDS refinement
__device__ void kth_of_cand(const uint32_t* cand_key, uint32_t cnt, uint32_t K,
                            uint32_t* hist, uint32_t* super,
                            uint32_t* s_bin, uint32_t* s_rank, uint32_t* s_kth) {
  const int tid = threadIdx.x;
  for (int i = tid; i < NBIN; i += BLOCK) hist[i] = 0u;
  __syncthreads();
  for (int i = tid; i < (int)cnt; i += BLOCK)
    atomicAdd(&hist[cand_key[i] >> 20], 1u);
  __syncthreads();
  find4096(hist, super, K, s_bin, s_rank);
  const uint32_t bA = *s_bin; const uint32_t rA = *s_rank;

  for (int i = tid; i < NBIN; i += BLOCK) hist[i] = 0u;
  __syncthreads();
  for (int i = tid; i < (int)cnt; i += BLOCK) {
    uint32_t key = cand_key[i];
    if ((key >> 20) == bA) atomicAdd(&hist[(key >> 8) & 0xFFFu], 1u);
  }
  __syncthreads();
  find4096(hist, super, rA, s_bin, s_rank);
  const uint32_t bB = *s_bin; const uint32_t rB = *s_rank;

  for (int i = tid; i < 256; i += BLOCK) hist[i] = 0u;
  __syncthreads();
  for (int i = tid; i < (int)cnt; i += BLOCK) {
    uint32_t key = cand_key[i];
    if ((key >> 8) == ((bA << 12) | bB)) atomicAdd(&hist[key & 0xFFu], 1u);
  }
  __syncthreads();
  if (tid == 0) {
    uint32_t acc = 0; uint32_t b3 = 0;
    for (int i = 255; i >= 0; --i) {
      if (acc + hist[i] >= rB) { b3 = (uint32_t)i; break; }
      acc += hist[i];
    }
    *s_kth = (bA << 20) | (bB << 8) | b3;
  }
  __syncthreads();
}

__device__ void gumbel_argmax_cand(const uint32_t* cand_key, const int* cand_idx,
                                   uint32_t cnt, float kth_scaled, float temp,
                                   uint32_t jbase, uint32_t* hist,
                                   int* out, int r) {
  const int tid = threadIdx.x;
  float bv = -INFINITY;
  int bi = 0x7FFFFFFF;
  for (int i = tid; i < (int)cnt; i += BLOCK) {
    float sc = key2f(cand_key[i]) / temp;
    if (sc >= kth_scaled) {
      int v = cand_idx[i];
      float g = gumbel_at(jbase + (uint32_t)v);
      float val = sc + g;
      if (val > bv || (val == bv && v < bi)) { bv = val; bi = v; }
    }
  }
  __syncthreads();
  float* rv = (float*)hist;
  int*   ri = (int*)(hist + BLOCK);
  rv[tid] = bv; ri[tid] = bi;
  __syncthreads();
  for (int s = BLOCK >> 1; s > 0; s >>= 1) {
    if (tid < s) {
      float ov = rv[tid + s]; int oi = ri[tid + s];
      if (ov > rv[tid] || (ov == rv[tid] && oi < ri[tid])) {
        rv[tid] = ov; ri[tid] = oi;
      }
    }
    __syncthreads();
  }
  if (tid == 0) out[r] = ri[0];
}

// ======================= R4 kernel 1: collect ==============================
// No global atomics: per-block LDS compaction -> private global slot.
__global__ __launch_bounds__(CBLOCK)
void collect_kernel(const float* __restrict__ logits, int V,
                    uint32_t* __restrict__ seg_cnts,
                    uint2* __restrict__ entries, uint32_t slot) {
  const int r   = blockIdx.x / SEG;
  const int seg = blockIdx.x % SEG;
  const int tid = threadIdx.x;
  const float* row = logits + (size_t)r * (size_t)V;
  const float4* row4 = (const float4*)row;
  const int n4 = V >> 2;
  const int chunk = (n4 + SEG - 1) / SEG;
  const int s4 = seg * chunk;
  const int e4 = min(n4, s4 + chunk);

  __shared__ uint32_t l_cnt;
  __shared__ uint32_t l_key[LCAP];
  __shared__ uint32_t l_idx[LCAP];
  if (tid == 0) l_cnt = 0u;
  __syncthreads();

  int i = s4 + tid;
  for (; i + 3 * CBLOCK < e4; i += 4 * CBLOCK) {
    float4 a = row4[i];
    float4 b = row4[i + CBLOCK];
    float4 c = row4[i + 2 * CBLOCK];
    float4 d = row4[i + 3 * CBLOCK];
#define PROC(vec, base)                                                        \
    {                                                                          \
      if (vec.x >= SPEC_F) { uint32_t p = atomicAdd(&l_cnt, 1u);               \
        if (p < LCAP) { l_key[p] = f2key(vec.x); l_idx[p] = ((base) << 2) + 0; } } \
      if (vec.y >= SPEC_F) { uint32_t p = atomicAdd(&l_cnt, 1u);               \
        if (p < LCAP) { l_key[p] = f2key(vec.y); l_idx[p] = ((base) << 2) + 1; } } \
      if (vec.z >= SPEC_F) { uint32_t p = atomicAdd(&l_cnt, 1u);               \
        if (p < LCAP) { l_key[p] = f2key(vec.z); l_idx[p] = ((base) << 2) + 2; } } \
      if (vec.w >= SPEC_F) { uint32_t p = atomicAdd(&l_cnt, 1u);               \
        if (p < LCAP) { l_key[p] = f2key(vec.w); l_idx[p] = ((base) << 2) + 3; } } \
    }
    PROC(a, i)
    PROC(b, i + CBLOCK)
    PROC(c, i + 2 * CBLOCK)
    PROC(d, i + 3 * CBLOCK)
  }
  for (; i < e4; i += CBLOCK) {
    float4 a = row4[i];
    PROC(a, i)
  }
#undef PROC
  if (seg == SEG - 1) {
    for (int j = (n4 << 2) + tid; j < V; j += CBLOCK) {
      float x = row[j];
      if (x >= SPEC_F) {
        uint32_t p = atomicAdd(&l_cnt, 1u);
        if (p < LCAP) { l_key[p] = f2key(x); l_idx[p] = (uint32_t)j; }
      }
    }
  }
  __syncthreads();
  const uint32_t c = l_cnt;
  uint2* dst = entries + (size_t)r * (size_t)(slot * SEG) + (size_t)seg * slot;
  const uint32_t w = (c < slot) ? c : slot;
  for (uint32_t k = tid; k < w; k += CBLOCK)
    dst[k] = make_uint2(l_key[k], l_idx[k]);
  if (tid == 0) seg_cnts[r * SEG + seg] = c;  // true count (may exceed slot)
}

// ======================= R4 kernel 2: finalize =============================
__global__ __launch_bounds__(BLOCK)
void finalize_kernel(const float* __restrict__ logits,
                     const float* __restrict__ temps,
                     const int* __restrict__ topk_p,
                     int* __restrict__ out, int V,
                     const uint32_t* __restrict__ seg_cnts,
                     const uint2* __restrict__ entries, uint32_t slot) {
  const int r = blockIdx.x;
  const int tid = threadIdx.x;
  const uint32_t K = (uint32_t)(*topk_p);
  const float temp = temps[r];
  const float* row = logits + (size_t)r * (size_t)V;
  const uint32_t jbase = (uint32_t)r * (uint32_t)V;

  __shared__ uint32_t hist[NBIN];
  __shared__ uint32_t super[64];
  __shared__ uint32_t cand_key[CAP];
  __shared__ int      cand_idx[CAP];
  __shared__ uint32_t soff[SEG + 1];
  __shared__ uint32_t s_ok;
  __shared__ uint32_t s_cnt, s_bin, s_rank, s_kth;
  __shared__ float    s_kth_scaled;

  // prefix-sum of per-segment counts + overflow check
  if (tid == 0) {
    uint32_t acc = 0; uint32_t ok = 1;
    for (int s = 0; s < SEG; ++s) {
      soff[s] = acc;
      uint32_t c = seg_cnts[r * SEG + s];
      if (c > slot) ok = 0;
      acc += (c < slot) ? c : slot;
    }
    soff[SEG] = acc;
    s_ok = ok;
  }
  __syncthreads();
  const uint32_t cnt = soff[SEG];

  if (s_ok && cnt >= K && cnt <= CAP) {
    const uint2* base = entries + (size_t)r * (size_t)(slot * SEG);
    for (int s = 0; s < SEG; ++s) {
      uint32_t c = soff[s + 1] - soff[s];
      const uint2* src = base + (size_t)s * slot;
      uint32_t off = soff[s];
      for (uint32_t k = tid; k < c; k += BLOCK) {
        uint2 e = src[k];
        cand_key[off + k] = e.x; cand_idx[off + k] = (int)e.y;
      }
    }
    __syncthreads();
    kth_of_cand(cand_key, cnt, K, hist, super, &s_bin, &s_rank, &s_kth);
    const uint32_t kth_key = s_kth;
    if (kth_key >= SPEC_KEY + SLACK) {
      if (tid == 0) s_kth_scaled = key2f(kth_key) / temp;
      __syncthreads();
      gumbel_argmax_cand(cand_key, cand_idx, cnt, s_kth_scaled, temp,
                         jbase, hist, out, r);
      return;
    }
    __syncthreads();
  }

  // ---------------- fallback: full histogram algorithm (L3-warm) ----------
  const int n4 = V >> 2;
  const float4* row4 = (const float4*)row;
  for (int i = tid; i < NBIN; i += BLOCK) hist[i] = 0u;
  if (tid == 0) s_cnt = 0u;
  __syncthreads();
  for (int i = tid; i < n4; i += BLOCK) {
    float4 x = row4[i];
    atomicAdd(&hist[f2key(x.x) >> 20], 1u);
    atomicAdd(&hist[f2key(x.y) >> 20], 1u);
    atomicAdd(&hist[f2key(x.z) >> 20], 1u);
    atomicAdd(&hist[f2key(x.w) >> 20], 1u);
  }
  for (int i = (n4 << 2) + tid; i < V; i += BLOCK)
    atomicAdd(&hist[f2key(row[i]) >> 20], 1u);
  __syncthreads();
  find4096(hist, super, K, &s_bin, &s_rank);
  const uint32_t b1 = s_bin;
  const uint32_t r1 = s_rank;

  uint32_t lo = b1 << 20;
  lo = (lo >= SLACK) ? (lo - SLACK) : 0u;
  for (int i = tid; i < n4; i += BLOCK) {
    float4 x = row4[i];
    float s[4] = {x.x, x.y, x.z, x.w};
#pragma unroll
    for (int q = 0; q < 4; ++q) {
      uint32_t key = f2key(s[q]);
      if (key >= lo) {
        uint32_t p = atomicAdd(&s_cnt, 1u);
        if (p < CAP) { cand_key[p] = key; cand_idx[p] = (i << 2) + q; }
      }
    }
  }
  for (int i = (n4 << 2) + tid; i < V; i += BLOCK) {
    uint32_t key = f2key(row[i]);
    if (key >= lo) {
      uint32_t p = atomicAdd(&s_cnt, 1u);
      if (p < CAP) { cand_key[p] = key; cand_idx[p] = i; }
    }
  }
  __syncthreads();
  const uint32_t cnt2 = s_cnt;

  if (cnt2 <= CAP) {
    kth_of_cand(cand_key, cnt2, K, hist, super, &s_bin, &s_rank, &s_kth);
    if (tid == 0) s_kth_scaled = key2f(s_kth) / temp;
    __syncthreads();
    gumbel_argmax_cand(cand_key, cand_idx, cnt2, s_kth_scaled, temp,
                       jbase, hist, out, r);
    return;
  }

  // pathological duplicate-heavy rows: refine from global memory
  for (int i = tid; i < NBIN; i += BLOCK) hist[i] = 0u;
  __syncthreads();
  for (int i = tid; i < V; i += BLOCK) {
    uint32_t key = f2key(row[i]);
    if ((key >> 20) == b1) atomicAdd(&hist[(key >> 8) & 0xFFFu], 1u);
  }
  __syncthreads();
  find4096(hist, super, r1, &s_bin, &s_rank);
  const uint32_t b2 = s_bin; const uint32_t r2 = s_rank;
  for (int i = tid; i < 256; i += BLOCK) hist[i] = 0u;
  __syncthreads();
  for (int i = tid; i < V; i += BLOCK) {
    uint32_t key = f2key(row[i]);
    if ((key >> 8) == ((b1 << 12) | b2)) atomicAdd(&hist[key & 0xFFu], 1u);
  }
  __syncthreads();
  if (tid == 0) {
    uint32_t acc = 0; uint32_t b3 = 0;
    for (int i = 255; i >= 0; --i) {
      if (acc + hist[i] >= r2) { b3 = (uint32_t)i; break; }
      acc += hist[i];
    }
    uint32_t kth = (b1 << 20) | (b2 << 8) | b3;
    s_kth = kth;
    s_kth_scaled = key2f(kth) / temp;
  }
  __syncthreads();
  const uint32_t kth_key = s_kth;
  const float kth_scaled = s_kth_scaled;
  uint32_t lo2 = (kth_key >= SLACK) ? (kth_key - SLACK) : 0u;

  float bv = -INFINITY;
  int bi = 0x7FFFFFFF;
  for (int i = tid; i < V; i += BLOCK) {
    float x = row[i];
    uint32_t key = f2key(x);
    if (key >= lo2) {
      float sc = x / temp;
      if (sc >= kth_scaled) {
        float g = gumbel_at(jbase + (uint32_t)i);
        float val = sc + g;
        if (val > bv || (val == bv && i < bi)) { bv = val; bi = i; }
      }
    }
  }
  __syncthreads();
  float* rv = (float*)hist;
  int*   ri = (int*)(hist + BLOCK);
  rv[tid] = bv; ri[tid] = bi;
  __syncthreads();
  for (int s = BLOCK >> 1; s > 0; s >>= 1) {
    if (tid < s) {
      float ov = rv[tid + s]; int oi = ri[tid + s];
      if (ov > rv[tid] || (ov == rv[tid] && oi < ri[tid])) {
        rv[tid] = ov; ri[tid] = oi;
      }
    }
    __syncthreads();
  }
  if (tid == 0) out[r] = ri[0];
}

// ============== monolithic R2 kernel (used only if ws too small) ===========
__global__ __launch_bounds__(BLOCK)
void sampler_mono(const float* __restrict__ logits,
                  const float* __restrict__ temps,
                  const int* __restrict__ topk_p,
                  int* __restrict__ out, int B, int V) {
  const int r = blockIdx.x;
  const int tid = threadIdx.x;
  const uint32_t K = (uint32_t)(*topk_p);
  const float temp = temps[r];
  const float* row = logits + (size_t)r * (size_t)V;
  const uint32_t jbase = (uint32_t)r * (uint32_t)V;

  __shared__ uint32_t hist[NBIN];
  __shared__ uint32_t super[64];
  __shared__ uint32_t cand_key[CAP];
  __shared__ int      cand_idx[CAP];
  __shared__ uint32_t s_cnt, s_bin, s_rank, s_kth;
  __shared__ float    s_kth_scaled;

  const int n4 = V >> 2;
  const float4* row4 = (const float4*)row;

  if (tid == 0) s_cnt = 0u;
  __syncthreads();
  for (int i = tid; i < n4; i += BLOCK) {
    float4 x = row4[i];
    float s[4] = {x.x, x.y, x.z, x.w};
#pragma unroll
    for (int q = 0; q < 4; ++q) {
      if (s[q] >= SPEC_F) {
        uint32_t p = atomicAdd(&s_cnt, 1u);
        if (p < CAP) { cand_key[p] = f2key(s[q]); cand_idx[p] = (i << 2) + q; }
      }
    }
  }
  for (int i = (n4 << 2) + tid; i < V; i += BLOCK) {
    float x = row[i];
    if (x >= SPEC_F) {
      uint32_t p = atomicAdd(&s_cnt, 1u);
      if (p < CAP) { cand_key[p] = f2key(x); cand_idx[p] = i; }
    }
  }
  __syncthreads();
  const uint32_t cnt = s_cnt;

  if (cnt >= K && cnt <= CAP) {
    kth_of_cand(cand_key, cnt, K, hist, super, &s_bin, &s_rank, &s_kth);
    const uint32_t kth_key = s_kth;
    if (kth_key >= SPEC_KEY + SLACK) {
      if (tid == 0) s_kth_scaled = key2f(kth_key) / temp;
      __syncthreads();
      gumbel_argmax_cand(cand_key, cand_idx, cnt, s_kth_scaled, temp,
                         jbase, hist, out, r);
      return;
    }
    __syncthreads();
  }

  for (int i = tid; i < NBIN; i += BLOCK) hist[i] = 0u;
  if (tid == 0) s_cnt = 0u;
  __syncthreads();
  for (int i = tid; i < n4; i += BLOCK) {
    float4 x = row4[i];
    atomicAdd(&hist[f2key(x.x) >> 20], 1u);
    atomicAdd(&hist[f2key(x.y) >> 20], 1u);
    atomicAdd(&hist[f2key(x.z) >> 20], 1u);
    atomicAdd(&hist[f2key(x.w) >> 20], 1u);
  }
  for (int i = (n4 << 2) + tid; i < V; i += BLOCK)
    atomicAdd(&hist[f2key(row[i]) >> 20], 1u);
  __syncthreads();
  find4096(hist, super, K, &s_bin, &s_rank);
  const uint32_t b1 = s_bin;
  const uint32_t r1 = s_rank;

  uint32_t lo = b1 << 20;
  lo = (lo >= SLACK) ? (lo - SLACK) : 0u;
  for (int i = tid; i < n4; i += BLOCK) {
    float4 x = row4[i];
    float s[4] = {x.x, x.y, x.z, x.w};
#pragma unroll
    for (int q = 0; q < 4; ++q) {
      uint32_t key = f2key(s[q]);
      if (key >= lo) {
        uint32_t p = atomicAdd(&s_cnt, 1u);
        if (p < CAP) { cand_key[p] = key; cand_idx[p] = (i << 2) + q; }
      }
    }
  }
  for (int i = (n4 << 2) + tid; i < V; i += BLOCK) {
    uint32_t key = f2key(row[i]);
    if (key >= lo) {
      uint32_t p = atomicAdd(&s_cnt, 1u);
      if (p < CAP) { cand_key[p] = key; cand_idx[p] = i; }
    }
  }
  __syncthreads();
  const uint32_t cnt2 = s_cnt;

  if (cnt2 <= CAP) {
    kth_of_cand(cand_key, cnt2, K, hist, super, &s_bin, &s_rank, &s_kth);
    if (tid == 0) s_kth_scaled = key2f(s_kth) / temp;
    __syncthreads();
    gumbel_argmax_cand(cand_key, cand_idx, cnt2, s_kth_scaled, temp,
                       jbase, hist, out, r);
    return;
  }

  for (int i = tid; i < NBIN; i += BLOCK) hist[i] = 0u;
  __syncthreads();
  for (int i = tid; i < V; i += BLOCK) {
    uint32_t key = f2key(row[i]);
    if ((key >> 20) == b1) atomicAdd(&hist[(key >> 8) & 0xFFFu], 1u);
  }
  __syncthreads();
  find4096(hist, super, r1, &s_bin, &s_rank);
  const uint32_t b2 = s_bin; const uint32_t r2 = s_rank;
  for (int i = tid; i < 256; i += BLOCK) hist[i] = 0u;
  __syncthreads();
  for (int i = tid; i < V; i += BLOCK) {
    uint32_t key = f2key(row[i]);
    if ((key >> 8) == ((b1 << 12) | b2)) atomicAdd(&hist[key & 0xFFu], 1u);
  }
  __syncthreads();
  if (tid == 0) {
    uint32_t acc = 0; uint32_t b3 = 0;
    for (int i = 255; i >= 0; --i) {
      if (acc + hist[i] >= r2) { b3 = (uint32_t)i; break; }
      acc += hist[i];
    }
    uint32_t kth = (b1 << 20) | (b2 << 8) | b3;
    s_kth = kth;
    s_kth_scaled = key2f(kth) / temp;
  }
  __syncthreads();
  const uint32_t kth_key = s_kth;
  const float kth_scaled = s_kth_scaled;
  uint32_t lo2 = (kth_key >= SLACK) ? (kth_key - SLACK) : 0u;

  float bv = -INFINITY;
  int bi = 0x7FFFFFFF;
  for (int i = tid; i < V; i += BLOCK) {
    float x = row[i];
    uint32_t key = f2key(x);
    if (key >= lo2) {
      float sc = x / temp;
      if (sc >= kth_scaled) {
        float g = gumbel_at(jbase + (uint32_t)i);
        float val = sc + g;
        if (val > bv || (val == bv && i < bi)) { bv = val; bi = i; }
      }
    }
  }
  __syncthreads();
  float* rv = (float*)hist;
  int*   ri = (int*)(hist + BLOCK);
  rv[tid] = bv; ri[tid] = bi;
  __syncthreads();
  for (int s = BLOCK >> 1; s > 0; s >>= 1) {
    if (tid < s) {
      float ov = rv[tid + s]; int oi = ri[tid + s];
      if (ov > rv[tid] || (ov == rv[tid] && oi < ri[tid])) {
        rv[tid] = ov; ri[tid] = oi;
      }
    }
    __syncthreads();
  }
  if (tid == 0) out[r] = ri[0];
}

extern "C" void kernel_launch(void* const* d_in, const int* in_sizes, int n_in,
                              void* d_out, int out_size, void* d_ws, size_t ws_size,
                              hipStream_t stream) {
  const float* logits = (const float*)d_in[0];
  const float* temps  = (const float*)d_in[1];
  const int*   topk   = (const int*)d_in[2];
  int* out = (int*)d_out;
  const int B = in_sizes[1];           // 256
  const int V = in_sizes[0] / B;       // 128000

  const size_t cnt_bytes = (size_t)B * SEG * sizeof(uint32_t);
  size_t slot = 0;
  if (ws_size > cnt_bytes + 4096) {
    size_t cap = (ws_size - cnt_bytes) / ((size_t)B * sizeof(uint2));
    if (cap > CAP) cap = CAP;
    slot = cap / SEG;
  }
  if (slot > LCAP) slot = LCAP;

  if (slot >= 32) {
    uint32_t* seg_cnts = (uint32_t*)d_ws;
    uint2* entries = (uint2*)((char*)d_ws + cnt_bytes);
    collect_kernel<<<B * SEG, CBLOCK, 0, stream>>>(logits, V, seg_cnts, entries,
                                                   (uint32_t)slot);
    finalize_kernel<<<B, BLOCK, 0, stream>>>(logits, temps, topk, out, V,
                                             seg_cnts, entries, (uint32_t)slot);
  } else {
    sampler_mono<<<B, BLOCK, 0, stream>>>(logits, temps, topk, out, B, V);
  }
}

// Round 6
// 37.123 us; speedup vs baseline: 12.0484x; 1.5947x over previous
//
#include <hip/hip_runtime.h>
#include <stdint.h>
#include <math.h>

// ---------------------------------------------------------------------------
// Sampler: temperature-scale -> top-k threshold -> Gumbel-max categorical.
// Exact reproduction of the JAX reference (threefry partitionable, key 42).
//
// R5 structure (two kernels, zero global atomics):
//   collect  : B*SEG blocks x 256 thr. 8-deep conditional float4 loads (full
//              segment's loads in flight at once), LDS-compact x >= SPEC_F,
//              copy to private slot in d_ws + per-segment count.
//   finalize : B blocks x 1024 thr. Parallel gather of <=2048 candidates,
//              exact kth via 3-level histogram with WAVE-PARALLEL bin select
//              (shfl suffix-scan + ballot), exact division filter, gumbel +
//              shfl argmax. Serial fallback path (full histogram re-read)
//              kept for speculation failure; mono kernel for tiny ws.
// ---------------------------------------------------------------------------

#define BLOCK 1024
#define CBLOCK 256
#define SEG 16
#define LCAP 128        // per-segment candidate slot (E[c]~50 for N(0,1))
#define NBIN  4096
#define CAP   4096
#define SLACK 64u
#define SPEC_F 2.5f
#define SPEC_KEY 0xC0200000u   // f2key(2.5f)

__device__ __forceinline__ uint32_t rotl32(uint32_t x, uint32_t r) {
  return (x << r) | (x >> (32u - r));
}

__device__ __forceinline__ uint32_t f2key(float x) {
  uint32_t b = __float_as_uint(x);
  return (b & 0x80000000u) ? ~b : (b | 0x80000000u);
}
__device__ __forceinline__ float key2f(uint32_t k) {
  uint32_t b = (k & 0x80000000u) ? (k & 0x7FFFFFFFu) : ~k;
  return __uint_as_float(b);
}

// Threefry-2x32, key = (0, 42)
__device__ __forceinline__ void tf2x32(uint32_t x0, uint32_t x1,
                                       uint32_t &o0, uint32_t &o1) {
  const uint32_t k0 = 0u, k1 = 42u;
  const uint32_t k2 = k0 ^ k1 ^ 0x1BD11BDAu;
  x0 += k0; x1 += k1;
#define TF_R(r) { x0 += x1; x1 = rotl32(x1, (r)); x1 ^= x0; }
  TF_R(13u) TF_R(15u) TF_R(26u) TF_R(6u)
  x0 += k1; x1 += k2 + 1u;
  TF_R(17u) TF_R(29u) TF_R(16u) TF_R(24u)
  x0 += k2; x1 += k0 + 2u;
  TF_R(13u) TF_R(15u) TF_R(26u) TF_R(6u)
  x0 += k0; x1 += k1 + 3u;
  TF_R(17u) TF_R(29u) TF_R(16u) TF_R(24u)
  x0 += k1; x1 += k2 + 4u;
  TF_R(13u) TF_R(15u) TF_R(26u) TF_R(6u)
  x0 += k2; x1 += k0 + 5u;
#undef TF_R
  o0 = x0; o1 = x1;
}

__device__ __forceinline__ float gumbel_at(uint32_t j) {
  uint32_t o0, o1;
  tf2x32(0u, j, o0, o1);
  uint32_t bits = o0 ^ o1;
  float f = __uint_as_float((bits >> 9) | 0x3F800000u) - 1.0f;
  const float TINY = 1.17549435e-38f;
  float u = (f == 0.0f) ? TINY : f;
  return -logf(-logf(u));
}

// ---- wave-parallel descending-rank select over 64 bins -------------------
// Called by tid<64 (one full wave). Thread t supplies v = count of bin (63-t).
// Returns (uniform across the wave) the bin holding the Kt-th largest and the
// 1-based rank within it.
__device__ __forceinline__ void wave_sel64(uint32_t v, uint32_t Kt,
                                           uint32_t &sel, uint32_t &rank) {
  const int lane = threadIdx.x & 63;
  uint32_t P = v;
#pragma unroll
  for (int d = 1; d < 64; d <<= 1) {
    uint32_t n = __shfl_up(P, d, 64);
    if (lane >= d) P += n;
  }
  unsigned long long m = __ballot(P >= Kt);
  int t0 = (int)__ffsll(m) - 1;     // P is non-decreasing in lane
  uint32_t Pt = __shfl(P, t0, 64);
  uint32_t vt = __shfl(v, t0, 64);
  sel = (uint32_t)(63 - t0);
  rank = Kt - (Pt - vt);
}

// ---- serial select (fallback paths only) ---------------------------------
__device__ void find4096(uint32_t* hist, uint32_t* super, uint32_t Kt,
                         uint32_t* s_bin, uint32_t* s_rank) {
  const int tid = threadIdx.x;
  if (tid < 64) {
    uint32_t s = 0;
    for (int i = 0; i < 64; ++i) s += hist[tid * 64 + i];
    super[tid] = s;
  }
  __syncthreads();
  if (tid == 0) {
    uint32_t acc = 0; int sb = 0;
    for (int s = 63; s >= 0; --s) {
      if (acc + super[s] >= Kt) { sb = s; break; }
      acc += super[s];
    }
    uint32_t bfound = (uint32_t)(sb * 64);
    for (int i = 63; i >= 0; --i) {
      uint32_t bin = (uint32_t)(sb * 64 + i);
      if (acc + hist[bin] >= Kt) { bfound = bin; break; }
      acc += hist[bin];
    }
    *s_bin = bfound; *s_rank = Kt - acc;
  }
  __syncthreads();
}

// exact kth-largest among cand[0:cnt] (serial select; fallback only)
__device__ void kth_of_cand(const uint32_t* cand_key, uint32_t cnt, uint32_t K,
                            uint32_t* hist, uint32_t* super,
                            uint32_t* s_bin, uint32_t* s_rank, uint32_t* s_kth) {
  const int tid = threadIdx.x;
  for (int i = tid; i < NBIN; i += BLOCK) hist[i] = 0u;
  __syncthreads();
  for (int i = tid; i < (int)cnt; i += BLOCK)
    atomicAdd(&hist[cand_key[i] >> 20], 1u);
  __syncthreads();
  find4096(hist, super, K, s_bin, s_rank);
  const uint32_t bA = *s_bin; const uint32_t rA = *s_rank;

  for (int i = tid; i < NBIN; i += BLOCK) hist[i] = 0u;
  __syncthreads();
  for (int i = tid; i < (int)cnt; i += BLOCK) {
    uint32_t key = cand_key[i];
    if ((key >> 20) == bA) atomicAdd(&hist[(key >> 8) & 0xFFFu], 1u);
  }
  __syncthreads();
  find4096(hist, super, rA, s_bin, s_rank);
  const uint32_t bB = *s_bin; const uint32_t rB = *s_rank;

  for (int i = tid; i < 256; i += BLOCK) hist[i] = 0u;
  __syncthreads();
  for (int i = tid; i < (int)cnt; i += BLOCK) {
    uint32_t key = cand_key[i];
    if ((key >> 8) == ((bA << 12) | bB)) atomicAdd(&hist[key & 0xFFu], 1u);
  }
  __syncthreads();
  if (tid == 0) {
    uint32_t acc = 0; uint32_t b3 = 0;
    for (int i = 255; i >= 0; --i) {
      if (acc + hist[i] >= rB) { b3 = (uint32_t)i; break; }
      acc += hist[i];
    }
    *s_kth = (bA << 20) | (bB << 8) | b3;
  }
  __syncthreads();
}

// gumbel-argmax over kept candidates; shfl wave-reduce + serial wave combine
__device__ void gumbel_argmax_cand(const uint32_t* cand_key, const int* cand_idx,
                                   uint32_t cnt, float kth_scaled, float temp,
                                   uint32_t jbase, uint32_t* scratch,
                                   int* out, int r) {
  const int tid = threadIdx.x;
  const int lane = tid & 63;
  const int wid = tid >> 6;
  float bv = -INFINITY;
  int bi = 0x7FFFFFFF;
  for (int i = tid; i < (int)cnt; i += blockDim.x) {
    float sc = key2f(cand_key[i]) / temp;
    if (sc >= kth_scaled) {
      int v = cand_idx[i];
      float g = gumbel_at(jbase + (uint32_t)v);
      float val = sc + g;
      if (val > bv || (val == bv && v < bi)) { bv = val; bi = v; }
    }
  }
#pragma unroll
  for (int d = 32; d > 0; d >>= 1) {
    float ov = __shfl_down(bv, d, 64);
    int oi = __shfl_down(bi, d, 64);
    if (ov > bv || (ov == bv && oi < bi)) { bv = ov; bi = oi; }
  }
  __syncthreads();                       // scratch may alias earlier LDS use
  float* rv = (float*)scratch;
  int*   ri = (int*)(scratch + 64);
  if (lane == 0) { rv[wid] = bv; ri[wid] = bi; }
  __syncthreads();
  if (tid == 0) {
    int nw = (int)(blockDim.x >> 6);
    float fv = rv[0]; int fi = ri[0];
    for (int w = 1; w < nw; ++w) {
      float ov = rv[w]; int oi = ri[w];
      if (ov > fv || (ov == fv && oi < fi)) { fv = ov; fi = oi; }
    }
    out[r] = fi;
  }
}

// ======================= kernel 1: collect =================================
__global__ __launch_bounds__(CBLOCK)
void collect_kernel(const float* __restrict__ logits, int V,
                    uint32_t* __restrict__ seg_cnts,
                    uint2* __restrict__ entries, uint32_t slot) {
  const int r   = blockIdx.x / SEG;
  const int seg = blockIdx.x % SEG;
  const int tid = threadIdx.x;
  const float* row = logits + (size_t)r * (size_t)V;
  const float4* row4 = (const float4*)row;
  const int n4 = V >> 2;
  const int chunk = (n4 + SEG - 1) / SEG;
  const int s4 = seg * chunk;
  const int e4 = min(n4, s4 + chunk);

  __shared__ uint32_t l_cnt;
  __shared__ uint32_t l_key[LCAP];
  __shared__ uint32_t l_idx[LCAP];
  if (tid == 0) l_cnt = 0u;
  __syncthreads();

  for (int i = s4 + tid; i < e4; i += 8 * CBLOCK) {
    float4 x[8];
#pragma unroll
    for (int k = 0; k < 8; ++k) {
      int idx = i + k * CBLOCK;
      x[k] = (idx < e4) ? row4[idx] : make_float4(0.f, 0.f, 0.f, 0.f);
    }
#pragma unroll
    for (int k = 0; k < 8; ++k) {
      int idx = i + k * CBLOCK;
      if (x[k].x >= SPEC_F) { uint32_t p = atomicAdd(&l_cnt, 1u);
        if (p < LCAP) { l_key[p] = f2key(x[k].x); l_idx[p] = ((uint32_t)idx << 2) + 0; } }
      if (x[k].y >= SPEC_F) { uint32_t p = atomicAdd(&l_cnt, 1u);
        if (p < LCAP) { l_key[p] = f2key(x[k].y); l_idx[p] = ((uint32_t)idx << 2) + 1; } }
      if (x[k].z >= SPEC_F) { uint32_t p = atomicAdd(&l_cnt, 1u);
        if (p < LCAP) { l_key[p] = f2key(x[k].z); l_idx[p] = ((uint32_t)idx << 2) + 2; } }
      if (x[k].w >= SPEC_F) { uint32_t p = atomicAdd(&l_cnt, 1u);
        if (p < LCAP) { l_key[p] = f2key(x[k].w); l_idx[p] = ((uint32_t)idx << 2) + 3; } }
    }
  }
  if (seg == SEG - 1) {
    for (int j = (n4 << 2) + tid; j < V; j += CBLOCK) {
      float x = row[j];
      if (x >= SPEC_F) {
        uint32_t p = atomicAdd(&l_cnt, 1u);
        if (p < LCAP) { l_key[p] = f2key(x); l_idx[p] = (uint32_t)j; }
      }
    }
  }
  __syncthreads();
  const uint32_t c = l_cnt;
  uint2* dst = entries + ((size_t)r * SEG + (size_t)seg) * slot;
  uint32_t w = c;
  if (w > slot) w = slot;
  if (w > LCAP) w = LCAP;
  for (uint32_t k = tid; k < w; k += CBLOCK)
    dst[k] = make_uint2(l_key[k], l_idx[k]);
  if (tid == 0) seg_cnts[r * SEG + seg] = c;   // true count (may exceed slot)
}

// ======================= kernel 2: finalize ================================
__global__ __launch_bounds__(BLOCK)
void finalize_kernel(const float* __restrict__ logits,
                     const float* __restrict__ temps,
                     const int* __restrict__ topk_p,
                     int* __restrict__ out, int V,
                     const uint32_t* __restrict__ seg_cnts,
                     const uint2* __restrict__ entries, uint32_t slot) {
  const int r = blockIdx.x;
  const int tid = threadIdx.x;
  const uint32_t K = (uint32_t)(*topk_p);
  const float temp = temps[r];
  const float* row = logits + (size_t)r * (size_t)V;
  const uint32_t jbase = (uint32_t)r * (uint32_t)V;

  __shared__ uint32_t hist[NBIN];
  __shared__ uint32_t super[64];
  __shared__ uint32_t cand_key[CAP];
  __shared__ int      cand_idx[CAP];
  __shared__ uint32_t scnt[SEG];
  __shared__ uint32_t soff[SEG + 1];
  __shared__ uint32_t s_ok;
  __shared__ uint32_t s_cnt, s_bin, s_rank, s_kth;
  __shared__ float    s_kth_scaled;

  if (tid < SEG) scnt[tid] = seg_cnts[r * SEG + tid];
  __syncthreads();
  if (tid == 0) {
    uint32_t acc = 0; uint32_t ok = 1;
    for (int s = 0; s < SEG; ++s) {
      soff[s] = acc;
      uint32_t c = scnt[s];
      if (c > slot) ok = 0;
      acc += (c < slot) ? c : slot;
    }
    soff[SEG] = acc;
    s_ok = ok;
  }
  __syncthreads();
  const uint32_t cnt = soff[SEG];

  if (s_ok && cnt >= K && cnt <= CAP) {
    // ---- parallel gather over the fixed SEG x slot grid ----
    const uint2* base = entries + (size_t)r * SEG * slot;
    const int tot = SEG * (int)slot;
    for (int idx = tid; idx < tot; idx += BLOCK) {
      int s = idx / (int)slot;
      int k = idx - s * (int)slot;
      if ((uint32_t)k < scnt[s]) {
        uint2 e = base[idx];
        uint32_t p = soff[s] + (uint32_t)k;
        cand_key[p] = e.x; cand_idx[p] = (int)e.y;
      }
    }
    __syncthreads();

    // ---- exact kth: 3-level histogram, wave-parallel select ----
    for (int i = tid; i < NBIN; i += BLOCK) hist[i] = 0u;
    __syncthreads();
    for (int i = tid; i < (int)cnt; i += BLOCK)
      atomicAdd(&hist[cand_key[i] >> 20], 1u);
    __syncthreads();
    if (tid < 64) {
      uint32_t s = 0;
      for (int i = 0; i < 64; ++i) s += hist[tid * 64 + i];
      super[tid] = s;
    }
    __syncthreads();
    if (tid < 64) {
      uint32_t sb, rs;
      wave_sel64(super[63 - tid], K, sb, rs);
      uint32_t s2, r2;
      wave_sel64(hist[sb * 64 + (63 - tid)], rs, s2, r2);
      if (tid == 0) { s_bin = sb * 64 + s2; s_rank = r2; }
    }
    __syncthreads();
    const uint32_t binA = s_bin;
    const uint32_t rA = s_rank;

    for (int i = tid; i < NBIN; i += BLOCK) hist[i] = 0u;
    __syncthreads();
    for (int i = tid; i < (int)cnt; i += BLOCK) {
      uint32_t key = cand_key[i];
      if ((key >> 20) == binA) atomicAdd(&hist[(key >> 8) & 0xFFFu], 1u);
    }
    __syncthreads();
    if (tid < 64) {
      uint32_t s = 0;
      for (int i = 0; i < 64; ++i) s += hist[tid * 64 + i];
      super[tid] = s;
    }
    __syncthreads();
    if (tid < 64) {
      uint32_t sb, rs;
      wave_sel64(super[63 - tid], rA, sb, rs);
      uint32_t s2, r2;
      wave_sel64(hist[sb * 64 + (63 - tid)], rs, s2, r2);
      if (tid == 0) { s_bin = sb * 64 + s2; s_rank = r2; }
    }
    __syncthreads();
    const uint32_t binB = s_bin;
    const uint32_t rB = s_rank;

    for (int i = tid; i < 256; i += BLOCK) hist[i] = 0u;
    __syncthreads();
    for (int i = tid; i < (int)cnt; i += BLOCK) {
      uint32_t key = cand_key[i];
      if ((key >> 8) == ((binA << 12) | binB)) atomicAdd(&hist[key & 0xFFu], 1u);
    }
    __syncthreads();
    if (tid < 64) {
      uint32_t mi = 63 - tid;   // mini index, descending
      uint32_t v = hist[mi * 4] + hist[mi * 4 + 1] + hist[mi * 4 + 2] + hist[mi * 4 + 3];
      uint32_t mm, rm;
      wave_sel64(v, rB, mm, rm);
      if (tid == 0) {
        uint32_t acc = 0; uint32_t b3 = mm * 4;
        for (int j = 3; j >= 0; --j) {
          uint32_t c = hist[mm * 4 + j];
          if (acc + c >= rm) { b3 = mm * 4 + (uint32_t)j; break; }
          acc += c;
        }
        uint32_t kth = (binA << 20) | (binB << 8) | b3;
        s_kth = kth;
        s_kth_scaled = key2f(kth) / temp;
      }
    }
    __syncthreads();
    const uint32_t kth_key = s_kth;
    if (kth_key >= SPEC_KEY + SLACK) {
      gumbel_argmax_cand(cand_key, cand_idx, cnt, s_kth_scaled, temp,
                         jbase, hist, out, r);
      return;
    }
    __syncthreads();
  }

  // ---------------- fallback: full histogram algorithm (L3-warm) ----------
  const int n4 = V >> 2;
  const float4* row4 = (const float4*)row;
  for (int i = tid; i < NBIN; i += BLOCK) hist[i] = 0u;
  if (tid == 0) s_cnt = 0u;
  __syncthreads();
  for (int i = tid; i < n4; i += BLOCK) {
    float4 x = row4[i];
    atomicAdd(&hist[f2key(x.x) >> 20], 1u);
    atomicAdd(&hist[f2key(x.y) >> 20], 1u);
    atomicAdd(&hist[f2key(x.z) >> 20], 1u);
    atomicAdd(&hist[f2key(x.w) >> 20], 1u);
  }
  for (int i = (n4 << 2) + tid; i < V; i += BLOCK)
    atomicAdd(&hist[f2key(row[i]) >> 20], 1u);
  __syncthreads();
  find4096(hist, super, K, &s_bin, &s_rank);
  const uint32_t b1 = s_bin;
  const uint32_t r1 = s_rank;

  uint32_t lo = b1 << 20;
  lo = (lo >= SLACK) ? (lo - SLACK) : 0u;
  for (int i = tid; i < n4; i += BLOCK) {
    float4 x = row4[i];
    float s[4] = {x.x, x.y, x.z, x.w};
#pragma unroll
    for (int q = 0; q < 4; ++q) {
      uint32_t key = f2key(s[q]);
      if (key >= lo) {
        uint32_t p = atomicAdd(&s_cnt, 1u);
        if (p < CAP) { cand_key[p] = key; cand_idx[p] = (i << 2) + q; }
      }
    }
  }
  for (int i = (n4 << 2) + tid; i < V; i += BLOCK) {
    uint32_t key = f2key(row[i]);
    if (key >= lo) {
      uint32_t p = atomicAdd(&s_cnt, 1u);
      if (p < CAP) { cand_key[p] = key; cand_idx[p] = i; }
    }
  }
  __syncthreads();
  const uint32_t cnt2 = s_cnt;

  if (cnt2 <= CAP) {
    kth_of_cand(cand_key, cnt2, K, hist, super, &s_bin, &s_rank, &s_kth);
    if (tid == 0) s_kth_scaled = key2f(s_kth) / temp;
    __syncthreads();
    gumbel_argmax_cand(cand_key, cand_idx, cnt2, s_kth_scaled, temp,
                       jbase, hist, out, r);
    return;
  }

  // pathological duplicate-heavy rows: refine from global memory
  for (int i = tid; i < NBIN; i += BLOCK) hist[i] = 0u;
  __syncthreads();
  for (int i = tid; i < V; i += BLOCK) {
    uint32_t key = f2key(row[i]);
    if ((key >> 20) == b1) atomicAdd(&hist[(key >> 8) & 0xFFFu], 1u);
  }
  __syncthreads();
  find4096(hist, super, r1, &s_bin, &s_rank);
  const uint32_t b2 = s_bin; const uint32_t r2 = s_rank;
  for (int i = tid; i < 256; i += BLOCK) hist[i] = 0u;
  __syncthreads();
  for (int i = tid; i < V; i += BLOCK) {
    uint32_t key = f2key(row[i]);
    if ((key >> 8) == ((b1 << 12) | b2)) atomicAdd(&hist[key & 0xFFu], 1u);
  }
  __syncthreads();
  if (tid == 0) {
    uint32_t acc = 0; uint32_t b3 = 0;
    for (int i = 255; i >= 0; --i) {
      if (acc + hist[i] >= r2) { b3 = (uint32_t)i; break; }
      acc += hist[i];
    }
    uint32_t kth = (b1 << 20) | (b2 << 8) | b3;
    s_kth = kth;
    s_kth_scaled = key2f(kth) / temp;
  }
  __syncthreads();
  const uint32_t kth_key = s_kth;
  const float kth_scaled = s_kth_scaled;
  uint32_t lo2 = (kth_key >= SLACK) ? (kth_key - SLACK) : 0u;

  float bv = -INFINITY;
  int bi = 0x7FFFFFFF;
  for (int i = tid; i < V; i += BLOCK) {
    float x = row[i];
    uint32_t key = f2key(x);
    if (key >= lo2) {
      float sc = x / temp;
      if (sc >= kth_scaled) {
        float g = gumbel_at(jbase + (uint32_t)i);
        float val = sc + g;
        if (val > bv || (val == bv && i < bi)) { bv = val; bi = i; }
      }
    }
  }
  __syncthreads();
  float* rv = (float*)hist;
  int*   ri = (int*)(hist + BLOCK);
  rv[tid] = bv; ri[tid] = bi;
  __syncthreads();
  for (int s = BLOCK >> 1; s > 0; s >>= 1) {
    if (tid < s) {
      float ov = rv[tid + s]; int oi = ri[tid + s];
      if (ov > rv[tid] || (ov == rv[tid] && oi < ri[tid])) {
        rv[tid] = ov; ri[tid] = oi;
      }
    }
    __syncthreads();
  }
  if (tid == 0) out[r] = ri[0];
}

// ============== monolithic kernel (used only if ws too small) ==============
__global__ __launch_bounds__(BLOCK)
void sampler_mono(const float* __restrict__ logits,
                  const float* __restrict__ temps,
                  const int* __restrict__ topk_p,
                  int* __restrict__ out, int B, int V) {
  const int r = blockIdx.x;
  const int tid = threadIdx.x;
  const uint32_t K = (uint32_t)(*topk_p);
  const float temp = temps[r];
  const float* row = logits + (size_t)r * (size_t)V;
  const uint32_t jbase = (uint32_t)r * (uint32_t)V;

  __shared__ uint32_t hist[NBIN];
  __shared__ uint32_t super[64];
  __shared__ uint32_t cand_key[CAP];
  __shared__ int      cand_idx[CAP];
  __shared__ uint32_t s_cnt, s_bin, s_rank, s_kth;
  __shared__ float    s_kth_scaled;

  const int n4 = V >> 2;
  const float4* row4 = (const float4*)row;

  if (tid == 0) s_cnt = 0u;
  __syncthreads();
  for (int i = tid; i < n4; i += BLOCK) {
    float4 x = row4[i];
    float s[4] = {x.x, x.y, x.z, x.w};
#pragma unroll
    for (int q = 0; q < 4; ++q) {
      if (s[q] >= SPEC_F) {
        uint32_t p = atomicAdd(&s_cnt, 1u);
        if (p < CAP) { cand_key[p] = f2key(s[q]); cand_idx[p] = (i << 2) + q; }
      }
    }
  }
  for (int i = (n4 << 2) + tid; i < V; i += BLOCK) {
    float x = row[i];
    if (x >= SPEC_F) {
      uint32_t p = atomicAdd(&s_cnt, 1u);
      if (p < CAP) { cand_key[p] = f2key(x); cand_idx[p] = i; }
    }
  }
  __syncthreads();
  const uint32_t cnt = s_cnt;

  if (cnt >= K && cnt <= CAP) {
    kth_of_cand(cand_key, cnt, K, hist, super, &s_bin, &s_rank, &s_kth);
    const uint32_t kth_key = s_kth;
    if (kth_key >= SPEC_KEY + SLACK) {
      if (tid == 0) s_kth_scaled = key2f(kth_key) / temp;
      __syncthreads();
      gumbel_argmax_cand(cand_key, cand_idx, cnt, s_kth_scaled, temp,
                         jbase, hist, out, r);
      return;
    }
    __syncthreads();
  }

  for (int i = tid; i < NBIN; i += BLOCK) hist[i] = 0u;
  if (tid == 0) s_cnt = 0u;
  __syncthreads();
  for (int i = tid; i < n4; i += BLOCK) {
    float4 x = row4[i];
    atomicAdd(&hist[f2key(x.x) >> 20], 1u);
    atomicAdd(&hist[f2key(x.y) >> 20], 1u);
    atomicAdd(&hist[f2key(x.z) >> 20], 1u);
    atomicAdd(&hist[f2key(x.w) >> 20], 1u);
  }
  for (int i = (n4 << 2) + tid; i < V; i += BLOCK)
    atomicAdd(&hist[f2key(row[i]) >> 20], 1u);
  __syncthreads();
  find4096(hist, super, K, &s_bin, &s_rank);
  const uint32_t b1 = s_bin;
  const uint32_t r1 = s_rank;

  uint32_t lo = b1 << 20;
  lo = (lo >= SLACK) ? (lo - SLACK) : 0u;
  for (int i = tid; i < n4; i += BLOCK) {
    float4 x = row4[i];
    float s[4] = {x.x, x.y, x.z, x.w};
#pragma unroll
    for (int q = 0; q < 4; ++q) {
      uint32_t key = f2key(s[q]);
      if (key >= lo) {
        uint32_t p = atomicAdd(&s_cnt, 1u);
        if (p < CAP) { cand_key[p] = key; cand_idx[p] = (i << 2) + q; }
      }
    }
  }
  for (int i = (n4 << 2) + tid; i < V; i += BLOCK) {
    uint32_t key = f2key(row[i]);
    if (key >= lo) {
      uint32_t p = atomicAdd(&s_cnt, 1u);
      if (p < CAP) { cand_key[p] = key; cand_idx[p] = i; }
    }
  }
  __syncthreads();
  const uint32_t cnt2 = s_cnt;

  if (cnt2 <= CAP) {
    kth_of_cand(cand_key, cnt2, K, hist, super, &s_bin, &s_rank, &s_kth);
    if (tid == 0) s_kth_scaled = key2f(s_kth) / temp;
    __syncthreads();
    gumbel_argmax_cand(cand_key, cand_idx, cnt2, s_kth_scaled, temp,
                       jbase, hist, out, r);
    return;
  }

  for (int i = tid; i < NBIN; i += BLOCK) hist[i] = 0u;
  __syncthreads();
  for (int i = tid; i < V; i += BLOCK) {
    uint32_t key = f2key(row[i]);
    if ((key >> 20) == b1) atomicAdd(&hist[(key >> 8) & 0xFFFu], 1u);
  }
  __syncthreads();
  find4096(hist, super, r1, &s_bin, &s_rank);
  const uint32_t b2 = s_bin; const uint32_t r2 = s_rank;
  for (int i = tid; i < 256; i += BLOCK) hist[i] = 0u;
  __syncthreads();
  for (int i = tid; i < V; i += BLOCK) {
    uint32_t key = f2key(row[i]);
    if ((key >> 8) == ((b1 << 12) | b2)) atomicAdd(&hist[key & 0xFFu], 1u);
  }
  __syncthreads();
  if (tid == 0) {
    uint32_t acc = 0; uint32_t b3 = 0;
    for (int i = 255; i >= 0; --i) {
      if (acc + hist[i] >= r2) { b3 = (uint32_t)i; break; }
      acc += hist[i];
    }
    uint32_t kth = (b1 << 20) | (b2 << 8) | b3;
    s_kth = kth;
    s_kth_scaled = key2f(kth) / temp;
  }
  __syncthreads();
  const uint32_t kth_key = s_kth;
  const float kth_scaled = s_kth_scaled;
  uint32_t lo2 = (kth_key >= SLACK) ? (kth_key - SLACK) : 0u;

  float bv = -INFINITY;
  int bi = 0x7FFFFFFF;
  for (int i = tid; i < V; i += BLOCK) {
    float x = row[i];
    uint32_t key = f2key(x);
    if (key >= lo2) {
      float sc = x / temp;
      if (sc >= kth_scaled) {
        float g = gumbel_at(jbase + (uint32_t)i);
        float val = sc + g;
        if (val > bv || (val == bv && i < bi)) { bv = val; bi = i; }
      }
    }
  }
  __syncthreads();
  float* rv = (float*)hist;
  int*   ri = (int*)(hist + BLOCK);
  rv[tid] = bv; ri[tid] = bi;
  __syncthreads();
  for (int s = BLOCK >> 1; s > 0; s >>= 1) {
    if (tid < s) {
      float ov = rv[tid + s]; int oi = ri[tid + s];
      if (ov > rv[tid] || (ov == rv[tid] && oi < ri[tid])) {
        rv[tid] = ov; ri[tid] = oi;
      }
    }
    __syncthreads();
  }
  if (tid == 0) out[r] = ri[0];
}

extern "C" void kernel_launch(void* const* d_in, const int* in_sizes, int n_in,
                              void* d_out, int out_size, void* d_ws, size_t ws_size,
                              hipStream_t stream) {
  const float* logits = (const float*)d_in[0];
  const float* temps  = (const float*)d_in[1];
  const int*   topk   = (const int*)d_in[2];
  int* out = (int*)d_out;
  const int B = in_sizes[1];           // 256
  const int V = in_sizes[0] / B;       // 128000

  const size_t cnt_bytes = (size_t)B * SEG * sizeof(uint32_t);
  size_t slot = 0;
  if (ws_size > cnt_bytes) {
    slot = (ws_size - cnt_bytes) / ((size_t)B * SEG * sizeof(uint2));
    if (slot > LCAP) slot = LCAP;
  }

  if (slot >= 32) {
    uint32_t* seg_cnts = (uint32_t*)d_ws;
    uint2* entries = (uint2*)((char*)d_ws + cnt_bytes);
    collect_kernel<<<B * SEG, CBLOCK, 0, stream>>>(logits, V, seg_cnts, entries,
                                                   (uint32_t)slot);
    finalize_kernel<<<B, BLOCK, 0, stream>>>(logits, temps, topk, out, V,
                                             seg_cnts, entries, (uint32_t)slot);
  } else {
    sampler_mono<<<B, BLOCK, 0, stream>>>(logits, temps, topk, out, B, V);
  }
}